// Round 4
// baseline (679.274 us; speedup 1.0000x reference)
//
#include <hip/hip_runtime.h>
#include <hip/hip_bf16.h>

typedef unsigned short u16;

#define T_SEQ 2048
#define NTOK 4096          // B*T
#define D_MODEL 2560
#define NQKV 4096          // H*Hd + 2*G*Hd
#define WIN 1024
#define ATTN_SCALE 0.0625f // 256^-0.5

typedef __attribute__((ext_vector_type(8))) short bf16x8;
typedef __attribute__((ext_vector_type(8))) unsigned short u16x8;
typedef __attribute__((ext_vector_type(4))) float f32x4;

__device__ __forceinline__ float bf2f(u16 u) {
  union { unsigned int i; float f; } c; c.i = ((unsigned int)u) << 16; return c.f;
}
__device__ __forceinline__ u16 f2bf(float f) {
  __hip_bfloat16 h = __float2bfloat16(f);
  return __builtin_bit_cast(u16, h);
}

// load 8 consecutive elements as bf16, from either a bf16 or an f32 array
template <int F32>
__device__ __forceinline__ u16x8 load8(const void* base, size_t off) {
  if constexpr (F32) {
    const float* p = (const float*)base + off;
    float4 a = *(const float4*)p;
    float4 b = *(const float4*)(p + 4);
    u16x8 r;
    r[0] = f2bf(a.x); r[1] = f2bf(a.y); r[2] = f2bf(a.z); r[3] = f2bf(a.w);
    r[4] = f2bf(b.x); r[5] = f2bf(b.y); r[6] = f2bf(b.z); r[7] = f2bf(b.w);
    return r;
  } else {
    return *(const u16x8*)((const u16*)base + off);
  }
}
template <int F32>
__device__ __forceinline__ ushort4 load4(const void* base, size_t off) {
  if constexpr (F32) {
    const float4 v = *(const float4*)((const float*)base + off);
    ushort4 r; r.x = f2bf(v.x); r.y = f2bf(v.y); r.z = f2bf(v.z); r.w = f2bf(v.w);
    return r;
  } else {
    return *(const ushort4*)((const u16*)base + off);
  }
}

// ---------------- dtype detector ------------------------------------------
// Even-index u16 words of x: bf16 data -> sane exponents; f32 data -> uniform.
__global__ __launch_bounds__(64) void detect_dtype(const u16* __restrict__ x,
                                                   int* __restrict__ flag) {
  int lane = threadIdx.x & 63;
  int cnt = 0;
  for (int i = 0; i < 32; ++i) {
    u16 w = x[(size_t)(lane * 32 + i) * 2];
    int e = (w >> 7) & 0xFF;
    if (e >= 100 && e <= 140) cnt++;
  }
#pragma unroll
  for (int m = 1; m < 64; m <<= 1) cnt += __shfl_xor(cnt, m, 64);
  if (lane == 0) *flag = (cnt > 1024) ? 0 : 1;   // 0 = bf16, 1 = f32
}

// ---------------- transpose: out[n][k] = bf16(in[k][n]); in [K][N] ---------
template <int DT>
__global__ __launch_bounds__(256) void transpose_w(
    const int* __restrict__ flag, const void* __restrict__ in,
    u16* __restrict__ out, int K, int N) {
  if (*flag != DT) return;
  __shared__ u16 tile[64][65];
  int kb = blockIdx.y * 64, nb = blockIdx.x * 64;
  int t = threadIdx.x;
  int c4 = (t & 15) * 4;
  int r0 = t >> 4;
#pragma unroll
  for (int i = 0; i < 4; ++i) {
    int r = r0 + i * 16;
    ushort4 v = load4<DT>(in, (size_t)(kb + r) * N + nb + c4);
    tile[r][c4] = v.x; tile[r][c4 + 1] = v.y; tile[r][c4 + 2] = v.z; tile[r][c4 + 3] = v.w;
  }
  __syncthreads();
#pragma unroll
  for (int i = 0; i < 4; ++i) {
    int n = r0 + i * 16;
    ushort4 v;
    v.x = tile[c4 + 0][n];
    v.y = tile[c4 + 1][n];
    v.z = tile[c4 + 2][n];
    v.w = tile[c4 + 3][n];
    *(ushort4*)(out + (size_t)(nb + n) * K + kb + c4) = v;
  }
}

// ---------------- GEMM: C[M,N] = A[M,K] * Bt[N,K]^T, fp32 accum -------------
// RA: A dtype (0=bf16,1=f32). WC: C dtype. Bt always internal bf16.
template <int RA, int WC>
__global__ __launch_bounds__(256, 2) void gemm_bt(
    const int* __restrict__ flag, int my_dt,
    const void* __restrict__ A, int lda, const u16* __restrict__ Bt, int ldb,
    void* __restrict__ C, int ldc, int K) {
  if (*flag != my_dt) return;
  __shared__ __align__(16) u16 As[128 * 32];
  __shared__ __align__(16) u16 Bs[128 * 32];
  const int tid = threadIdx.x;
  const int wave = tid >> 6, lane = tid & 63;
  const int quad = lane >> 4, l16 = lane & 15;
  const int mblk = blockIdx.y * 128, nblk = blockIdx.x * 128;
  const int wm = (wave >> 1) * 64, wn = (wave & 1) * 64;
  f32x4 acc[4][4] = {};
  for (int k0 = 0; k0 < K; k0 += 32) {
#pragma unroll
    for (int i = 0; i < 2; ++i) {
      int u = i * 256 + tid;          // 8-elem unit 0..511
      int row = u >> 2;               // 4 units (32 elems) per row
      int kb = (u & 3) * 8;
      *(u16x8*)(As + row * 32 + kb) = load8<RA>(A, (size_t)(mblk + row) * lda + k0 + kb);
      *(u16x8*)(Bs + row * 32 + kb) = *(const u16x8*)(Bt + (size_t)(nblk + row) * ldb + k0 + kb);
    }
    __syncthreads();
    bf16x8 aF[4], bF[4];
#pragma unroll
    for (int t = 0; t < 4; ++t) {
      aF[t] = *(const bf16x8*)(As + (wm + t * 16 + l16) * 32 + quad * 8);
      bF[t] = *(const bf16x8*)(Bs + (wn + t * 16 + l16) * 32 + quad * 8);
    }
#pragma unroll
    for (int tm = 0; tm < 4; ++tm)
#pragma unroll
      for (int tn = 0; tn < 4; ++tn)
        acc[tm][tn] = __builtin_amdgcn_mfma_f32_16x16x32_bf16(aF[tm], bF[tn], acc[tm][tn], 0, 0, 0);
    __syncthreads();
  }
#pragma unroll
  for (int tm = 0; tm < 4; ++tm)
#pragma unroll
    for (int tn = 0; tn < 4; ++tn)
#pragma unroll
      for (int r = 0; r < 4; ++r) {
        int row = mblk + wm + tm * 16 + quad * 4 + r;   // verified C/D layout
        int col = nblk + wn + tn * 16 + l16;
        if constexpr (WC)
          ((float*)C)[(size_t)row * ldc + col] = acc[tm][tn][r];
        else
          ((u16*)C)[(size_t)row * ldc + col] = f2bf(acc[tm][tn][r]);
      }
}

// ---------------- RMSNorm on q (8 heads) and k (4 groups), in place ---------
template <int DT>
__global__ __launch_bounds__(256) void rmsnorm_qk(
    const int* __restrict__ flag, u16* __restrict__ qkv,
    const void* __restrict__ q_scale, const void* __restrict__ k_scale) {
  if (*flag != DT) return;
  int wv = blockIdx.x * 4 + (threadIdx.x >> 6);
  int lane = threadIdx.x & 63;
  int token = wv / 12, j = wv - token * 12;
  const void* sc = (j < 8) ? q_scale : k_scale;
  int col = (j < 8) ? j * 256 : 2048 + (j - 8) * 256;
  u16* p = qkv + (size_t)token * NQKV + col;
  int d = lane * 4;
  ushort4 raw = *(const ushort4*)(p + d);
  float x0 = bf2f(raw.x), x1 = bf2f(raw.y), x2 = bf2f(raw.z), x3 = bf2f(raw.w);
  float sum = x0 * x0 + x1 * x1 + x2 * x2 + x3 * x3;
#pragma unroll
  for (int m = 1; m < 64; m <<= 1) sum += __shfl_xor(sum, m, 64);
  float r = rsqrtf(sum * (1.0f / 256.0f) + 1e-6f);
  ushort4 sraw = load4<DT>(sc, d);
  ushort4 o;
  o.x = f2bf(x0 * r * (1.0f + bf2f(sraw.x)));
  o.y = f2bf(x1 * r * (1.0f + bf2f(sraw.y)));
  o.z = f2bf(x2 * r * (1.0f + bf2f(sraw.z)));
  o.w = f2bf(x3 * r * (1.0f + bf2f(sraw.w)));
  *(ushort4*)(p + d) = o;
}

// ---------------- fused sliding-window attention (in-place over Q region) ---
// grid (T/64, H, B); block 256 = 4 waves; wave w owns queries [t0+16w, +16).
__global__ __launch_bounds__(256) void attn_fused(u16* __restrict__ qkv) {
  const int qt = blockIdx.x, h = blockIdx.y, b = blockIdx.z;
  const int g = h & 3;                    // reference reshape => group = h % 4
  const int tid = threadIdx.x;
  const int wave = tid >> 6, lane = tid & 63;
  const int quad = lane >> 4, l16 = lane & 15;
  const int t0 = qt * 64;
  const int tw = t0 + wave * 16;
  __shared__ __align__(16) u16 Ks[32 * 256];
  __shared__ __align__(16) u16 Vs[32 * 256];
  __shared__ __align__(16) u16 Ps[4][16 * 32];
  bf16x8 qF[8];
  {
    const u16* qrow = qkv + (size_t)(b * T_SEQ + tw + l16) * NQKV + h * 256;
#pragma unroll
    for (int kc = 0; kc < 8; ++kc)
      qF[kc] = *(const bf16x8*)(qrow + kc * 32 + quad * 8);
  }
  f32x4 o[16] = {};
  float mrow[4] = {-3.0e38f, -3.0e38f, -3.0e38f, -3.0e38f};
  float lrow[4] = {0.f, 0.f, 0.f, 0.f};
  int s_lo = t0 - (WIN - 1); if (s_lo < 0) s_lo = 0; s_lo &= ~31;
  const int s_hi = t0 + 63;
  for (int sb = s_lo; sb <= s_hi; sb += 32) {
#pragma unroll
    for (int i = 0; i < 4; ++i) {
      int u = i * 256 + tid;            // 16B unit 0..1023
      int row = u >> 5, cb = u & 31;
      const u16* gK = qkv + (size_t)(b * T_SEQ + sb + row) * NQKV + 2048 + g * 256 + cb * 8;
      *(u16x8*)(Ks + u * 8) = *(const u16x8*)gK;
      *(u16x8*)(Vs + u * 8) = *(const u16x8*)(gK + 1024);
    }
    __syncthreads();
    f32x4 st[2] = {};
#pragma unroll
    for (int nt = 0; nt < 2; ++nt)
#pragma unroll
      for (int kc = 0; kc < 8; ++kc) {
        bf16x8 kF = *(const bf16x8*)(Ks + (nt * 16 + l16) * 256 + kc * 32 + quad * 8);
        st[nt] = __builtin_amdgcn_mfma_f32_16x16x32_bf16(qF[kc], kF, st[nt], 0, 0, 0);
      }
    float alpha[4];
#pragma unroll
    for (int r = 0; r < 4; ++r) {
      int t = tw + quad * 4 + r;
      float v0 = st[0][r] * ATTN_SCALE;
      float v1 = st[1][r] * ATTN_SCALE;
      int c0s = sb + l16, c1s = sb + 16 + l16;
      v0 = (c0s <= t && c0s > t - WIN) ? v0 : -3.0e38f;
      v1 = (c1s <= t && c1s > t - WIN) ? v1 : -3.0e38f;
      float mx = fmaxf(v0, v1);
      mx = fmaxf(mx, __shfl_xor(mx, 1, 64));
      mx = fmaxf(mx, __shfl_xor(mx, 2, 64));
      mx = fmaxf(mx, __shfl_xor(mx, 4, 64));
      mx = fmaxf(mx, __shfl_xor(mx, 8, 64));
      float mnew = fmaxf(mrow[r], mx);
      float mcl = fmaxf(mnew, -1.0e30f);      // finite clamp; masked block => p=0
      alpha[r] = __expf(mrow[r] - mcl);
      mrow[r] = mnew;
      float p0 = __expf(v0 - mcl);
      float p1 = __expf(v1 - mcl);
      Ps[wave][(quad * 4 + r) * 32 + l16] = f2bf(p0);
      Ps[wave][(quad * 4 + r) * 32 + 16 + l16] = f2bf(p1);
      float ps = p0 + p1;
      ps += __shfl_xor(ps, 1, 64);
      ps += __shfl_xor(ps, 2, 64);
      ps += __shfl_xor(ps, 4, 64);
      ps += __shfl_xor(ps, 8, 64);
      lrow[r] = lrow[r] * alpha[r] + ps;
    }
#pragma unroll
    for (int nt = 0; nt < 16; ++nt)
#pragma unroll
      for (int r = 0; r < 4; ++r) o[nt][r] *= alpha[r];
    __syncthreads();
    bf16x8 pF = *(const bf16x8*)(&Ps[wave][l16 * 32 + quad * 8]);
#pragma unroll
    for (int nt = 0; nt < 16; ++nt) {
      bf16x8 vF;
#pragma unroll
      for (int jj = 0; jj < 8; ++jj)
        vF[jj] = (short)Vs[(quad * 8 + jj) * 256 + nt * 16 + l16];
      o[nt] = __builtin_amdgcn_mfma_f32_16x16x32_bf16(pF, vF, o[nt], 0, 0, 0);
    }
    __syncthreads();
  }
#pragma unroll
  for (int r = 0; r < 4; ++r) {
    float inv = 1.0f / lrow[r];
    int t = tw + quad * 4 + r;
    u16* orow = qkv + (size_t)(b * T_SEQ + t) * NQKV + h * 256;
#pragma unroll
    for (int nt = 0; nt < 16; ++nt)
      orow[nt * 16 + l16] = f2bf(o[nt][r] * inv);
  }
}

// ---------------------------------------------------------------------------
extern "C" void kernel_launch(void* const* d_in, const int* in_sizes, int n_in,
                              void* d_out, int out_size, void* d_ws, size_t ws_size,
                              hipStream_t stream) {
  const void* x       = d_in[0];
  const void* Wq      = d_in[1];
  const void* Wk      = d_in[2];
  const void* Wv      = d_in[3];
  const void* Wo      = d_in[4];
  const void* q_scale = d_in[5];
  const void* k_scale = d_in[6];

  // ws: [flag 256B][qkv 4096x4096 bf16 33.5MB][WT 10.5MB] = 44MB
  int* flag = (int*)d_ws;
  u16* qkv  = (u16*)d_ws + 128;
  u16* WT   = qkv + (size_t)NTOK * NQKV;

  detect_dtype<<<1, 64, 0, stream>>>((const u16*)x, flag);

#define RUN2(stmt0, stmt1) do { stmt0; stmt1; } while (0)
  // Q projection
  RUN2((transpose_w<0><<<dim3(32, 40), 256, 0, stream>>>(flag, Wq, WT, D_MODEL, 2048)),
       (transpose_w<1><<<dim3(32, 40), 256, 0, stream>>>(flag, Wq, WT, D_MODEL, 2048)));
  RUN2((gemm_bt<0, 0><<<dim3(16, 32), 256, 0, stream>>>(flag, 0, x, D_MODEL, WT, D_MODEL, qkv, NQKV, D_MODEL)),
       (gemm_bt<1, 0><<<dim3(16, 32), 256, 0, stream>>>(flag, 1, x, D_MODEL, WT, D_MODEL, qkv, NQKV, D_MODEL)));
  // K projection
  RUN2((transpose_w<0><<<dim3(16, 40), 256, 0, stream>>>(flag, Wk, WT, D_MODEL, 1024)),
       (transpose_w<1><<<dim3(16, 40), 256, 0, stream>>>(flag, Wk, WT, D_MODEL, 1024)));
  RUN2((gemm_bt<0, 0><<<dim3(8, 32), 256, 0, stream>>>(flag, 0, x, D_MODEL, WT, D_MODEL, qkv + 2048, NQKV, D_MODEL)),
       (gemm_bt<1, 0><<<dim3(8, 32), 256, 0, stream>>>(flag, 1, x, D_MODEL, WT, D_MODEL, qkv + 2048, NQKV, D_MODEL)));
  // V projection
  RUN2((transpose_w<0><<<dim3(16, 40), 256, 0, stream>>>(flag, Wv, WT, D_MODEL, 1024)),
       (transpose_w<1><<<dim3(16, 40), 256, 0, stream>>>(flag, Wv, WT, D_MODEL, 1024)));
  RUN2((gemm_bt<0, 0><<<dim3(8, 32), 256, 0, stream>>>(flag, 0, x, D_MODEL, WT, D_MODEL, qkv + 3072, NQKV, D_MODEL)),
       (gemm_bt<1, 0><<<dim3(8, 32), 256, 0, stream>>>(flag, 1, x, D_MODEL, WT, D_MODEL, qkv + 3072, NQKV, D_MODEL)));
  // Gemma qk-norm
  RUN2((rmsnorm_qk<0><<<dim3(12288), 256, 0, stream>>>(flag, qkv, q_scale, k_scale)),
       (rmsnorm_qk<1><<<dim3(12288), 256, 0, stream>>>(flag, qkv, q_scale, k_scale)));
  // sliding-window attention (internal bf16 only, dtype-agnostic)
  attn_fused<<<dim3(T_SEQ / 64, 8, 2), 256, 0, stream>>>(qkv);
  // output projection: out = attn (qkv cols 0..2047) @ Wo, out dtype = input dtype
  RUN2((transpose_w<0><<<dim3(40, 32), 256, 0, stream>>>(flag, Wo, WT, 2048, D_MODEL)),
       (transpose_w<1><<<dim3(40, 32), 256, 0, stream>>>(flag, Wo, WT, 2048, D_MODEL)));
  RUN2((gemm_bt<0, 0><<<dim3(20, 32), 256, 0, stream>>>(flag, 0, qkv, NQKV, WT, 2048, d_out, D_MODEL, 2048)),
       (gemm_bt<0, 1><<<dim3(20, 32), 256, 0, stream>>>(flag, 1, qkv, NQKV, WT, 2048, d_out, D_MODEL, 2048)));
#undef RUN2
}

// Round 5
// 581.750 us; speedup vs baseline: 1.1676x; 1.1676x over previous
//
#include <hip/hip_runtime.h>
#include <hip/hip_bf16.h>

typedef unsigned short u16;

#define T_SEQ 2048
#define NTOK 4096          // B*T
#define D_MODEL 2560
#define NQKV 4096          // H*Hd + 2*G*Hd
#define WIN 1024
#define ATTN_SCALE 0.0625f // 256^-0.5
#define KROW 264           // padded Ks row (u16): 528B stride -> conflict-free

typedef __attribute__((ext_vector_type(8))) short bf16x8;
typedef __attribute__((ext_vector_type(8))) unsigned short u16x8;
typedef __attribute__((ext_vector_type(4))) float f32x4;

__device__ __forceinline__ float bf2f(u16 u) {
  union { unsigned int i; float f; } c; c.i = ((unsigned int)u) << 16; return c.f;
}
__device__ __forceinline__ u16 f2bf(float f) {
  __hip_bfloat16 h = __float2bfloat16(f);
  return __builtin_bit_cast(u16, h);
}

// load 8 consecutive elements as bf16 from f32 array
__device__ __forceinline__ u16x8 load8f(const float* p) {
  float4 a = *(const float4*)p;
  float4 b = *(const float4*)(p + 4);
  u16x8 r;
  r[0] = f2bf(a.x); r[1] = f2bf(a.y); r[2] = f2bf(a.z); r[3] = f2bf(a.w);
  r[4] = f2bf(b.x); r[5] = f2bf(b.y); r[6] = f2bf(b.z); r[7] = f2bf(b.w);
  return r;
}

// ---------------- weight transpose: out[n][k] = bf16(in[k][n]), in f32 -----
__global__ __launch_bounds__(256) void transpose_w(
    const float* __restrict__ in, u16* __restrict__ out, int K, int N) {
  __shared__ u16 tile[64][65];
  int kb = blockIdx.y * 64, nb = blockIdx.x * 64;
  int t = threadIdx.x;
  int c4 = (t & 15) * 4;
  int r0 = t >> 4;
#pragma unroll
  for (int i = 0; i < 4; ++i) {
    int r = r0 + i * 16;
    float4 v = *(const float4*)(in + (size_t)(kb + r) * N + nb + c4);
    tile[r][c4] = f2bf(v.x); tile[r][c4 + 1] = f2bf(v.y);
    tile[r][c4 + 2] = f2bf(v.z); tile[r][c4 + 3] = f2bf(v.w);
  }
  __syncthreads();
#pragma unroll
  for (int i = 0; i < 4; ++i) {
    int n = r0 + i * 16;
    ushort4 v;
    v.x = tile[c4 + 0][n];
    v.y = tile[c4 + 1][n];
    v.z = tile[c4 + 2][n];
    v.w = tile[c4 + 3][n];
    *(ushort4*)(out + (size_t)(nb + n) * K + kb + c4) = v;
  }
}

// ---------------- V transpose: Vt[(b*4+g)][dim][t] = qkv[b,t][3072+g*256+dim]
__global__ __launch_bounds__(256) void v_transpose(
    const u16* __restrict__ qkv, u16* __restrict__ Vt) {
  int bg = blockIdx.z; int b = bg >> 2, g = bg & 3;
  __shared__ u16 tile[64][65];
  int tb = blockIdx.y * 64, db = blockIdx.x * 64;
  const u16* in = qkv + (size_t)(b * T_SEQ) * NQKV + 3072 + g * 256;
  u16* out = Vt + (size_t)bg * 256 * T_SEQ;
  int t = threadIdx.x;
  int c4 = (t & 15) * 4;
  int r0 = t >> 4;
#pragma unroll
  for (int i = 0; i < 4; ++i) {
    int r = r0 + i * 16;   // token within tile
    ushort4 v = *(const ushort4*)(in + (size_t)(tb + r) * NQKV + db + c4);
    tile[r][c4] = v.x; tile[r][c4 + 1] = v.y; tile[r][c4 + 2] = v.z; tile[r][c4 + 3] = v.w;
  }
  __syncthreads();
#pragma unroll
  for (int i = 0; i < 4; ++i) {
    int n = r0 + i * 16;   // dim within tile
    ushort4 v;
    v.x = tile[c4 + 0][n];
    v.y = tile[c4 + 1][n];
    v.z = tile[c4 + 2][n];
    v.w = tile[c4 + 3][n];
    *(ushort4*)(out + (size_t)(db + n) * T_SEQ + tb + c4) = v;
  }
}

// ---------------- GEMM: C[M,N] = A[M,K] * Bt[N,K]^T, fp32 accum -------------
// RA: A dtype (0=bf16,1=f32). WC: C dtype (0=bf16,1=f32). Bt always bf16.
template <int RA, int WC>
__global__ __launch_bounds__(256, 2) void gemm_bt(
    const void* __restrict__ A, int lda, const u16* __restrict__ Bt, int ldb,
    void* __restrict__ C, int ldc, int K) {
  __shared__ __align__(16) u16 As[128 * 32];
  __shared__ __align__(16) u16 Bs[128 * 32];
  const int tid = threadIdx.x;
  const int wave = tid >> 6, lane = tid & 63;
  const int quad = lane >> 4, l16 = lane & 15;
  const int mblk = blockIdx.y * 128, nblk = blockIdx.x * 128;
  const int wm = (wave >> 1) * 64, wn = (wave & 1) * 64;
  f32x4 acc[4][4] = {};
  for (int k0 = 0; k0 < K; k0 += 32) {
#pragma unroll
    for (int i = 0; i < 2; ++i) {
      int u = i * 256 + tid;          // 8-elem unit 0..511
      int row = u >> 2;               // 4 units (32 elems) per row
      int kb = (u & 3) * 8;
      if constexpr (RA)
        *(u16x8*)(As + row * 32 + kb) = load8f((const float*)A + (size_t)(mblk + row) * lda + k0 + kb);
      else
        *(u16x8*)(As + row * 32 + kb) = *(const u16x8*)((const u16*)A + (size_t)(mblk + row) * lda + k0 + kb);
      *(u16x8*)(Bs + row * 32 + kb) = *(const u16x8*)(Bt + (size_t)(nblk + row) * ldb + k0 + kb);
    }
    __syncthreads();
    bf16x8 aF[4], bF[4];
#pragma unroll
    for (int t = 0; t < 4; ++t) {
      aF[t] = *(const bf16x8*)(As + (wm + t * 16 + l16) * 32 + quad * 8);
      bF[t] = *(const bf16x8*)(Bs + (wn + t * 16 + l16) * 32 + quad * 8);
    }
#pragma unroll
    for (int tm = 0; tm < 4; ++tm)
#pragma unroll
      for (int tn = 0; tn < 4; ++tn)
        acc[tm][tn] = __builtin_amdgcn_mfma_f32_16x16x32_bf16(aF[tm], bF[tn], acc[tm][tn], 0, 0, 0);
    __syncthreads();
  }
#pragma unroll
  for (int tm = 0; tm < 4; ++tm)
#pragma unroll
    for (int tn = 0; tn < 4; ++tn)
#pragma unroll
      for (int r = 0; r < 4; ++r) {
        int row = mblk + wm + tm * 16 + quad * 4 + r;   // verified C/D layout
        int col = nblk + wn + tn * 16 + l16;
        if constexpr (WC)
          ((float*)C)[(size_t)row * ldc + col] = acc[tm][tn][r];
        else
          ((u16*)C)[(size_t)row * ldc + col] = f2bf(acc[tm][tn][r]);
      }
}

// ---------------- RMSNorm on q (8 heads) and k (4 groups), in place ---------
__global__ __launch_bounds__(256) void rmsnorm_qk(
    u16* __restrict__ qkv, const float* __restrict__ q_scale,
    const float* __restrict__ k_scale) {
  int wv = blockIdx.x * 4 + (threadIdx.x >> 6);
  int lane = threadIdx.x & 63;
  int token = wv / 12, j = wv - token * 12;
  const float* sc = (j < 8) ? q_scale : k_scale;
  int col = (j < 8) ? j * 256 : 2048 + (j - 8) * 256;
  u16* p = qkv + (size_t)token * NQKV + col;
  int d = lane * 4;
  ushort4 raw = *(const ushort4*)(p + d);
  float x0 = bf2f(raw.x), x1 = bf2f(raw.y), x2 = bf2f(raw.z), x3 = bf2f(raw.w);
  float sum = x0 * x0 + x1 * x1 + x2 * x2 + x3 * x3;
#pragma unroll
  for (int m = 1; m < 64; m <<= 1) sum += __shfl_xor(sum, m, 64);
  float r = rsqrtf(sum * (1.0f / 256.0f) + 1e-6f);
  float4 sv = *(const float4*)(sc + d);
  ushort4 o;
  o.x = f2bf(x0 * r * (1.0f + sv.x));
  o.y = f2bf(x1 * r * (1.0f + sv.y));
  o.z = f2bf(x2 * r * (1.0f + sv.z));
  o.w = f2bf(x3 * r * (1.0f + sv.w));
  *(ushort4*)(p + d) = o;
}

// ---------------- fused sliding-window attention (in-place over Q region) ---
// grid (T/64, H, B); block 256 = 4 waves; wave w owns queries [t0+16w, +16).
// K staged padded (conflict-free); V staged dim-major from pre-transposed Vt.
__global__ __launch_bounds__(256) void attn_fused(
    u16* __restrict__ qkv, const u16* __restrict__ Vt) {
  const int qt = blockIdx.x, h = blockIdx.y, b = blockIdx.z;
  const int g = h & 3;                    // reference reshape => group = h % 4
  const int tid = threadIdx.x;
  const int wave = tid >> 6, lane = tid & 63;
  const int quad = lane >> 4, l16 = lane & 15;
  const int t0 = qt * 64;
  const int tw = t0 + wave * 16;
  __shared__ __align__(16) u16 Ks[32 * KROW];   // [kv 32][dim 256 +pad]
  __shared__ __align__(16) u16 Vs[256 * 32];    // [dim 256][kv 32]
  __shared__ __align__(16) u16 Ps[4][16 * 32];
  bf16x8 qF[8];
  {
    const u16* qrow = qkv + (size_t)(b * T_SEQ + tw + l16) * NQKV + h * 256;
#pragma unroll
    for (int kc = 0; kc < 8; ++kc)
      qF[kc] = *(const bf16x8*)(qrow + kc * 32 + quad * 8);
  }
  const u16* vt_base = Vt + (size_t)(b * 4 + g) * 256 * T_SEQ;
  f32x4 o[16] = {};
  float mrow[4] = {-3.0e38f, -3.0e38f, -3.0e38f, -3.0e38f};
  float lrow[4] = {0.f, 0.f, 0.f, 0.f};
  int s_lo = t0 - (WIN - 1); if (s_lo < 0) s_lo = 0; s_lo &= ~31;
  const int s_hi = t0 + 63;
  for (int sb = s_lo; sb <= s_hi; sb += 32) {
    // ---- stage K [32 kv][256 dim] (padded rows) + V [256 dim][32 kv] ----
#pragma unroll
    for (int i = 0; i < 4; ++i) {
      int u = i * 256 + tid;            // 16B unit 0..1023
      int krow = u >> 5, kcb = u & 31;
      *(u16x8*)(Ks + krow * KROW + kcb * 8) =
          *(const u16x8*)(qkv + (size_t)(b * T_SEQ + sb + krow) * NQKV + 2048 + g * 256 + kcb * 8);
      int dim = u >> 2, kvp = (u & 3) * 8;
      *(u16x8*)(Vs + dim * 32 + kvp) =
          *(const u16x8*)(vt_base + (size_t)dim * T_SEQ + sb + kvp);
    }
    __syncthreads();
    // ---- QK^T: C[qrow 16][kvrow 32] ----
    f32x4 st[2] = {};
#pragma unroll
    for (int nt = 0; nt < 2; ++nt)
#pragma unroll
      for (int kc = 0; kc < 8; ++kc) {
        bf16x8 kF = *(const bf16x8*)(Ks + (nt * 16 + l16) * KROW + kc * 32 + quad * 8);
        st[nt] = __builtin_amdgcn_mfma_f32_16x16x32_bf16(qF[kc], kF, st[nt], 0, 0, 0);
      }
    // ---- online softmax (all-finite arithmetic) ----
    float alpha[4];
#pragma unroll
    for (int r = 0; r < 4; ++r) {
      int t = tw + quad * 4 + r;
      float v0 = st[0][r] * ATTN_SCALE;
      float v1 = st[1][r] * ATTN_SCALE;
      int c0s = sb + l16, c1s = sb + 16 + l16;
      v0 = (c0s <= t && c0s > t - WIN) ? v0 : -3.0e38f;
      v1 = (c1s <= t && c1s > t - WIN) ? v1 : -3.0e38f;
      float mx = fmaxf(v0, v1);
      mx = fmaxf(mx, __shfl_xor(mx, 1, 64));
      mx = fmaxf(mx, __shfl_xor(mx, 2, 64));
      mx = fmaxf(mx, __shfl_xor(mx, 4, 64));
      mx = fmaxf(mx, __shfl_xor(mx, 8, 64));
      float mnew = fmaxf(mrow[r], mx);
      float mcl = fmaxf(mnew, -1.0e30f);      // finite clamp; masked block => p=0
      alpha[r] = __expf(mrow[r] - mcl);
      mrow[r] = mnew;
      float p0 = __expf(v0 - mcl);
      float p1 = __expf(v1 - mcl);
      Ps[wave][(quad * 4 + r) * 32 + l16] = f2bf(p0);
      Ps[wave][(quad * 4 + r) * 32 + 16 + l16] = f2bf(p1);
      float ps = p0 + p1;
      ps += __shfl_xor(ps, 1, 64);
      ps += __shfl_xor(ps, 2, 64);
      ps += __shfl_xor(ps, 4, 64);
      ps += __shfl_xor(ps, 8, 64);
      lrow[r] = lrow[r] * alpha[r] + ps;
    }
#pragma unroll
    for (int nt = 0; nt < 16; ++nt)
#pragma unroll
      for (int r = 0; r < 4; ++r) o[nt][r] *= alpha[r];
    __syncthreads();   // Ps write->read ordering
    // ---- P·V: A = P (16x32), B = Vs[dim][kv] -> vector b128 frags ----
    bf16x8 pF = *(const bf16x8*)(&Ps[wave][l16 * 32 + quad * 8]);
#pragma unroll
    for (int nt = 0; nt < 16; ++nt) {
      bf16x8 vF = *(const bf16x8*)(Vs + (nt * 16 + l16) * 32 + quad * 8);
      o[nt] = __builtin_amdgcn_mfma_f32_16x16x32_bf16(pF, vF, o[nt], 0, 0, 0);
    }
    __syncthreads();   // protect Ks/Vs/Ps before next staging
  }
  // ---- epilogue: write in place over this block's Q rows ----
#pragma unroll
  for (int r = 0; r < 4; ++r) {
    float inv = 1.0f / lrow[r];
    int t = tw + quad * 4 + r;
    u16* orow = qkv + (size_t)(b * T_SEQ + t) * NQKV + h * 256;
#pragma unroll
    for (int nt = 0; nt < 16; ++nt)
      orow[nt * 16 + l16] = f2bf(o[nt][r] * inv);
  }
}

// ---------------------------------------------------------------------------
extern "C" void kernel_launch(void* const* d_in, const int* in_sizes, int n_in,
                              void* d_out, int out_size, void* d_ws, size_t ws_size,
                              hipStream_t stream) {
  const float* x       = (const float*)d_in[0];
  const float* Wq      = (const float*)d_in[1];
  const float* Wk      = (const float*)d_in[2];
  const float* Wv      = (const float*)d_in[3];
  const float* Wo      = (const float*)d_in[4];
  const float* q_scale = (const float*)d_in[5];
  const float* k_scale = (const float*)d_in[6];

  // ws: qkv [4096][4096] bf16 (33.5MB) + WT/Vt scratch (10.5MB) = 44MB
  u16* qkv = (u16*)d_ws;
  u16* WT  = qkv + (size_t)NTOK * NQKV;   // also reused as Vt (8.4MB <= 10.5MB)

  // Q projection
  transpose_w<<<dim3(32, 40), 256, 0, stream>>>(Wq, WT, D_MODEL, 2048);
  gemm_bt<1, 0><<<dim3(16, 32), 256, 0, stream>>>(x, D_MODEL, WT, D_MODEL, qkv, NQKV, D_MODEL);
  // K projection
  transpose_w<<<dim3(16, 40), 256, 0, stream>>>(Wk, WT, D_MODEL, 1024);
  gemm_bt<1, 0><<<dim3(8, 32), 256, 0, stream>>>(x, D_MODEL, WT, D_MODEL, qkv + 2048, NQKV, D_MODEL);
  // V projection
  transpose_w<<<dim3(16, 40), 256, 0, stream>>>(Wv, WT, D_MODEL, 1024);
  gemm_bt<1, 0><<<dim3(8, 32), 256, 0, stream>>>(x, D_MODEL, WT, D_MODEL, qkv + 3072, NQKV, D_MODEL);
  // Gemma qk-norm
  rmsnorm_qk<<<dim3(12288), 256, 0, stream>>>(qkv, q_scale, k_scale);
  // V -> dim-major copy for conflict-free PV fragments (into WT slot)
  v_transpose<<<dim3(4, 32, 8), 256, 0, stream>>>(qkv, WT);
  // sliding-window attention, output in place over Q region (cols 0..2047)
  attn_fused<<<dim3(T_SEQ / 64, 8, 2), 256, 0, stream>>>(qkv, WT);
  // output projection (f32 out)
  transpose_w<<<dim3(40, 32), 256, 0, stream>>>(Wo, WT, 2048, D_MODEL);
  gemm_bt<0, 1><<<dim3(20, 32), 256, 0, stream>>>(qkv, NQKV, WT, 2048, d_out, D_MODEL, 2048);
}

// Round 6
// 404.986 us; speedup vs baseline: 1.6773x; 1.4365x over previous
//
#include <hip/hip_runtime.h>
#include <hip/hip_bf16.h>

typedef unsigned short u16;

#define T_SEQ 2048
#define NTOK 4096          // B*T
#define D_MODEL 2560
#define NQKV 4096          // H*Hd + 2*G*Hd
#define WIN 1024
#define ATTN_SCALE 0.0625f // 256^-0.5
#define SMAX 17.0f         // |score*scale| <= 16.13 (RMSNorm => |q|=|k|=16)
#define KROW 264           // padded Ks row (u16): 528B stride -> conflict-free

typedef __attribute__((ext_vector_type(8))) short bf16x8;
typedef __attribute__((ext_vector_type(8))) unsigned short u16x8;
typedef __attribute__((ext_vector_type(4))) float f32x4;

__device__ __forceinline__ float bf2f(u16 u) {
  union { unsigned int i; float f; } c; c.i = ((unsigned int)u) << 16; return c.f;
}
__device__ __forceinline__ u16 f2bf(float f) {
  __hip_bfloat16 h = __float2bfloat16(f);
  return __builtin_bit_cast(u16, h);
}
__device__ __forceinline__ u16x8 load8f(const float* p) {
  float4 a = *(const float4*)p;
  float4 b = *(const float4*)(p + 4);
  u16x8 r;
  r[0] = f2bf(a.x); r[1] = f2bf(a.y); r[2] = f2bf(a.z); r[3] = f2bf(a.w);
  r[4] = f2bf(b.x); r[5] = f2bf(b.y); r[6] = f2bf(b.z); r[7] = f2bf(b.w);
  return r;
}
__device__ __forceinline__ void gload_lds16(const u16* g, u16* l) {
  __builtin_amdgcn_global_load_lds(
      (const __attribute__((address_space(1))) void*)g,
      (__attribute__((address_space(3))) void*)l, 16, 0, 0);
}

// ---------------- x f32 -> bf16 bulk convert -------------------------------
__global__ __launch_bounds__(256) void cvt_f32_bf16(
    const float* __restrict__ in, u16* __restrict__ out) {
  size_t i = ((size_t)blockIdx.x * 256 + threadIdx.x) * 8;
  *(u16x8*)(out + i) = load8f(in + i);
}

// ---------------- weight transpose: out[n][k] = bf16(in[k][n]), in f32 -----
__global__ __launch_bounds__(256) void transpose_w(
    const float* __restrict__ in, u16* __restrict__ out, int K, int N) {
  __shared__ u16 tile[64][65];
  int kb = blockIdx.y * 64, nb = blockIdx.x * 64;
  int t = threadIdx.x;
  int c4 = (t & 15) * 4;
  int r0 = t >> 4;
#pragma unroll
  for (int i = 0; i < 4; ++i) {
    int r = r0 + i * 16;
    float4 v = *(const float4*)(in + (size_t)(kb + r) * N + nb + c4);
    tile[r][c4] = f2bf(v.x); tile[r][c4 + 1] = f2bf(v.y);
    tile[r][c4 + 2] = f2bf(v.z); tile[r][c4 + 3] = f2bf(v.w);
  }
  __syncthreads();
#pragma unroll
  for (int i = 0; i < 4; ++i) {
    int n = r0 + i * 16;
    ushort4 v;
    v.x = tile[c4 + 0][n];
    v.y = tile[c4 + 1][n];
    v.z = tile[c4 + 2][n];
    v.w = tile[c4 + 3][n];
    *(ushort4*)(out + (size_t)(nb + n) * K + kb + c4) = v;
  }
}

// ---------------- V transpose: Vt[(b*4+g)][dim][t] = qkv[b,t][3072+g*256+dim]
__global__ __launch_bounds__(256) void v_transpose(
    const u16* __restrict__ qkv, u16* __restrict__ Vt) {
  int bg = blockIdx.z; int b = bg >> 2, g = bg & 3;
  __shared__ u16 tile[64][65];
  int tb = blockIdx.y * 64, db = blockIdx.x * 64;
  const u16* in = qkv + (size_t)(b * T_SEQ) * NQKV + 3072 + g * 256;
  u16* out = Vt + (size_t)bg * 256 * T_SEQ;
  int t = threadIdx.x;
  int c4 = (t & 15) * 4;
  int r0 = t >> 4;
#pragma unroll
  for (int i = 0; i < 4; ++i) {
    int r = r0 + i * 16;   // token within tile
    ushort4 v = *(const ushort4*)(in + (size_t)(tb + r) * NQKV + db + c4);
    tile[r][c4] = v.x; tile[r][c4 + 1] = v.y; tile[r][c4 + 2] = v.z; tile[r][c4 + 3] = v.w;
  }
  __syncthreads();
#pragma unroll
  for (int i = 0; i < 4; ++i) {
    int n = r0 + i * 16;   // dim within tile
    ushort4 v;
    v.x = tile[c4 + 0][n];
    v.y = tile[c4 + 1][n];
    v.z = tile[c4 + 2][n];
    v.w = tile[c4 + 3][n];
    *(ushort4*)(out + (size_t)(db + n) * T_SEQ + tb + c4) = v;
  }
}

// ---------------- fast GEMM (m97): bf16 A/Bt, global_load_lds staging -------
template <int WC>
__global__ __launch_bounds__(256, 2) void gemm_fast(
    const u16* __restrict__ A, int lda, const u16* __restrict__ Bt, int ldb,
    void* __restrict__ C, int ldc, int K) {
  __shared__ __align__(16) u16 As[128 * 32];
  __shared__ __align__(16) u16 Bs[128 * 32];
  const int tid = threadIdx.x;
  const int wave = tid >> 6, lane = tid & 63;
  const int quad = lane >> 4, l16 = lane & 15;
  const int mblk = blockIdx.y * 128, nblk = blockIdx.x * 128;
  const int wm = (wave >> 1) * 64, wn = (wave & 1) * 64;
  f32x4 acc[4][4] = {};
  const int c0 = wave * 2;
  for (int k0 = 0; k0 < K; k0 += 32) {
#pragma unroll
    for (int i = 0; i < 2; ++i) {
      int c = c0 + i;
      int flat = c * 64 + lane;       // 16B unit 0..511
      int row = flat >> 2;
      int kb = (flat & 3) * 8;
      gload_lds16(A + (size_t)(mblk + row) * lda + k0 + kb, As + c * 512);
      gload_lds16(Bt + (size_t)(nblk + row) * ldb + k0 + kb, Bs + c * 512);
    }
    __syncthreads();
    bf16x8 aF[4], bF[4];
#pragma unroll
    for (int t = 0; t < 4; ++t) {
      aF[t] = *(const bf16x8*)(As + (wm + t * 16 + l16) * 32 + quad * 8);
      bF[t] = *(const bf16x8*)(Bs + (wn + t * 16 + l16) * 32 + quad * 8);
    }
#pragma unroll
    for (int tm = 0; tm < 4; ++tm)
#pragma unroll
      for (int tn = 0; tn < 4; ++tn)
        acc[tm][tn] = __builtin_amdgcn_mfma_f32_16x16x32_bf16(aF[tm], bF[tn], acc[tm][tn], 0, 0, 0);
    __syncthreads();
  }
#pragma unroll
  for (int tm = 0; tm < 4; ++tm)
#pragma unroll
    for (int tn = 0; tn < 4; ++tn)
#pragma unroll
      for (int r = 0; r < 4; ++r) {
        int row = mblk + wm + tm * 16 + quad * 4 + r;
        int col = nblk + wn + tn * 16 + l16;
        if constexpr (WC)
          ((float*)C)[(size_t)row * ldc + col] = acc[tm][tn][r];
        else
          ((u16*)C)[(size_t)row * ldc + col] = f2bf(acc[tm][tn][r]);
      }
}

// ---------------- fallback GEMM: f32 A, manual staging ----------------------
__global__ __launch_bounds__(256, 2) void gemm_f32a(
    const float* __restrict__ A, int lda, const u16* __restrict__ Bt, int ldb,
    u16* __restrict__ C, int ldc, int K) {
  __shared__ __align__(16) u16 As[128 * 32];
  __shared__ __align__(16) u16 Bs[128 * 32];
  const int tid = threadIdx.x;
  const int wave = tid >> 6, lane = tid & 63;
  const int quad = lane >> 4, l16 = lane & 15;
  const int mblk = blockIdx.y * 128, nblk = blockIdx.x * 128;
  const int wm = (wave >> 1) * 64, wn = (wave & 1) * 64;
  f32x4 acc[4][4] = {};
  for (int k0 = 0; k0 < K; k0 += 32) {
#pragma unroll
    for (int i = 0; i < 2; ++i) {
      int u = i * 256 + tid;
      int row = u >> 2;
      int kb = (u & 3) * 8;
      *(u16x8*)(As + row * 32 + kb) = load8f(A + (size_t)(mblk + row) * lda + k0 + kb);
      *(u16x8*)(Bs + row * 32 + kb) = *(const u16x8*)(Bt + (size_t)(nblk + row) * ldb + k0 + kb);
    }
    __syncthreads();
    bf16x8 aF[4], bF[4];
#pragma unroll
    for (int t = 0; t < 4; ++t) {
      aF[t] = *(const bf16x8*)(As + (wm + t * 16 + l16) * 32 + quad * 8);
      bF[t] = *(const bf16x8*)(Bs + (wn + t * 16 + l16) * 32 + quad * 8);
    }
#pragma unroll
    for (int tm = 0; tm < 4; ++tm)
#pragma unroll
      for (int tn = 0; tn < 4; ++tn)
        acc[tm][tn] = __builtin_amdgcn_mfma_f32_16x16x32_bf16(aF[tm], bF[tn], acc[tm][tn], 0, 0, 0);
    __syncthreads();
  }
#pragma unroll
  for (int tm = 0; tm < 4; ++tm)
#pragma unroll
    for (int tn = 0; tn < 4; ++tn)
#pragma unroll
      for (int r = 0; r < 4; ++r) {
        int row = mblk + wm + tm * 16 + quad * 4 + r;
        int col = nblk + wn + tn * 16 + l16;
        C[(size_t)row * ldc + col] = f2bf(acc[tm][tn][r]);
      }
}

// ---------------- RMSNorm on q (8 heads) and k (4 groups), in place ---------
__global__ __launch_bounds__(256) void rmsnorm_qk(
    u16* __restrict__ qkv, const float* __restrict__ q_scale,
    const float* __restrict__ k_scale) {
  int wv = blockIdx.x * 4 + (threadIdx.x >> 6);
  int lane = threadIdx.x & 63;
  int token = wv / 12, j = wv - token * 12;
  const float* sc = (j < 8) ? q_scale : k_scale;
  int col = (j < 8) ? j * 256 : 2048 + (j - 8) * 256;
  u16* p = qkv + (size_t)token * NQKV + col;
  int d = lane * 4;
  ushort4 raw = *(const ushort4*)(p + d);
  float x0 = bf2f(raw.x), x1 = bf2f(raw.y), x2 = bf2f(raw.z), x3 = bf2f(raw.w);
  float sum = x0 * x0 + x1 * x1 + x2 * x2 + x3 * x3;
#pragma unroll
  for (int m = 1; m < 64; m <<= 1) sum += __shfl_xor(sum, m, 64);
  float r = rsqrtf(sum * (1.0f / 256.0f) + 1e-6f);
  float4 sv = *(const float4*)(sc + d);
  ushort4 o;
  o.x = f2bf(x0 * r * (1.0f + sv.x));
  o.y = f2bf(x1 * r * (1.0f + sv.y));
  o.z = f2bf(x2 * r * (1.0f + sv.z));
  o.w = f2bf(x3 * r * (1.0f + sv.w));
  *(ushort4*)(p + d) = o;
}

// ---------------- fused sliding-window attention (in-place over Q region) ---
// Fixed-max softmax (SMAX): no running max, no alpha, no o-rescale.
// grid (T/64, H, B); block 256 = 4 waves; wave w owns queries [t0+16w, +16).
__global__ __launch_bounds__(256) void attn_fused(
    u16* __restrict__ qkv, const u16* __restrict__ Vt) {
  const int qt = blockIdx.x, h = blockIdx.y, b = blockIdx.z;
  const int g = h & 3;                    // reference reshape => group = h % 4
  const int tid = threadIdx.x;
  const int wave = tid >> 6, lane = tid & 63;
  const int quad = lane >> 4, l16 = lane & 15;
  const int t0 = qt * 64;
  const int tw = t0 + wave * 16;
  __shared__ __align__(16) u16 Ks[32 * KROW];   // [kv 32][dim 256 +pad]
  __shared__ __align__(16) u16 Vs[256 * 32];    // [dim 256][kv 32]
  __shared__ __align__(16) u16 Ps[4][16 * 32];
  bf16x8 qF[8];
  {
    const u16* qrow = qkv + (size_t)(b * T_SEQ + tw + l16) * NQKV + h * 256;
#pragma unroll
    for (int kc = 0; kc < 8; ++kc)
      qF[kc] = *(const bf16x8*)(qrow + kc * 32 + quad * 8);
  }
  const u16* vt_base = Vt + (size_t)(b * 4 + g) * 256 * T_SEQ;
  f32x4 o[16] = {};
  float lsum[4] = {0.f, 0.f, 0.f, 0.f};
  int s_lo = t0 - (WIN - 1); if (s_lo < 0) s_lo = 0; s_lo &= ~31;
  const int s_hi = t0 + 63;
  for (int sb = s_lo; sb <= s_hi; sb += 32) {
    // ---- stage K [32 kv][256 dim] (padded rows) + V [256 dim][32 kv] ----
#pragma unroll
    for (int i = 0; i < 4; ++i) {
      int u = i * 256 + tid;            // 16B unit 0..1023
      int krow = u >> 5, kcb = u & 31;
      *(u16x8*)(Ks + krow * KROW + kcb * 8) =
          *(const u16x8*)(qkv + (size_t)(b * T_SEQ + sb + krow) * NQKV + 2048 + g * 256 + kcb * 8);
      int dim = u >> 2, kvp = (u & 3) * 8;
      *(u16x8*)(Vs + dim * 32 + kvp) =
          *(const u16x8*)(vt_base + (size_t)dim * T_SEQ + sb + kvp);
    }
    __syncthreads();
    // ---- QK^T: C[qrow 16][kvrow 32] ----
    f32x4 st[2] = {};
#pragma unroll
    for (int nt = 0; nt < 2; ++nt)
#pragma unroll
      for (int kc = 0; kc < 8; ++kc) {
        bf16x8 kF = *(const bf16x8*)(Ks + (nt * 16 + l16) * KROW + kc * 32 + quad * 8);
        st[nt] = __builtin_amdgcn_mfma_f32_16x16x32_bf16(qF[kc], kF, st[nt], 0, 0, 0);
      }
    // ---- fixed-max softmax: p = exp(s*scale - SMAX), masked -> 0 ----
    const bool full = (sb + 31 <= tw) && (sb >= tw + 15 - (WIN - 1));
#pragma unroll
    for (int r = 0; r < 4; ++r) {
      float v0 = st[0][r] * ATTN_SCALE - SMAX;
      float v1 = st[1][r] * ATTN_SCALE - SMAX;
      if (!full) {
        int t = tw + quad * 4 + r;
        int c0s = sb + l16, c1s = c0s + 16;
        v0 = (c0s <= t && c0s > t - WIN) ? v0 : -3.0e38f;
        v1 = (c1s <= t && c1s > t - WIN) ? v1 : -3.0e38f;
      }
      float p0 = __expf(v0);
      float p1 = __expf(v1);
      Ps[wave][(quad * 4 + r) * 32 + l16] = f2bf(p0);
      Ps[wave][(quad * 4 + r) * 32 + 16 + l16] = f2bf(p1);
      lsum[r] += p0 + p1;
    }
    __syncthreads();   // Ps write->read ordering
    // ---- P·V: A = P (16x32), B = Vs[dim][kv] ----
    bf16x8 pF = *(const bf16x8*)(&Ps[wave][l16 * 32 + quad * 8]);
#pragma unroll
    for (int nt = 0; nt < 16; ++nt) {
      bf16x8 vF = *(const bf16x8*)(Vs + (nt * 16 + l16) * 32 + quad * 8);
      o[nt] = __builtin_amdgcn_mfma_f32_16x16x32_bf16(pF, vF, o[nt], 0, 0, 0);
    }
    __syncthreads();   // protect Ks/Vs/Ps before next staging
  }
  // ---- row sums across the 16 columns held per lane group ----
#pragma unroll
  for (int r = 0; r < 4; ++r) {
    float s = lsum[r];
    s += __shfl_xor(s, 1, 64);
    s += __shfl_xor(s, 2, 64);
    s += __shfl_xor(s, 4, 64);
    s += __shfl_xor(s, 8, 64);
    lsum[r] = s;
  }
  // ---- epilogue: write in place over this block's Q rows ----
#pragma unroll
  for (int r = 0; r < 4; ++r) {
    float inv = 1.0f / lsum[r];
    int t = tw + quad * 4 + r;
    u16* orow = qkv + (size_t)(b * T_SEQ + t) * NQKV + h * 256;
#pragma unroll
    for (int nt = 0; nt < 16; ++nt)
      orow[nt * 16 + l16] = f2bf(o[nt][r] * inv);
  }
}

// ---------------------------------------------------------------------------
extern "C" void kernel_launch(void* const* d_in, const int* in_sizes, int n_in,
                              void* d_out, int out_size, void* d_ws, size_t ws_size,
                              hipStream_t stream) {
  const float* x       = (const float*)d_in[0];
  const float* Wq      = (const float*)d_in[1];
  const float* Wk      = (const float*)d_in[2];
  const float* Wv      = (const float*)d_in[3];
  const float* Wo      = (const float*)d_in[4];
  const float* q_scale = (const float*)d_in[5];
  const float* k_scale = (const float*)d_in[6];

  u16* qkv = (u16*)d_ws;                                   // 33.5 MB
  const size_t BIG_WS = (size_t)NTOK * NQKV * 2            // qkv
                      + (size_t)NTOK * D_MODEL * 2         // xbf
                      + (size_t)NQKV * D_MODEL * 2;        // WT (all QKV)

  if (ws_size >= BIG_WS) {
    // ---- big-ws path: bf16 x + fused QKV GEMM with global_load_lds ----
    u16* xbf = qkv + (size_t)NTOK * NQKV;                  // 21 MB (later: Vt)
    u16* WT  = xbf + (size_t)NTOK * D_MODEL;               // 21 MB (later: WoT)
    cvt_f32_bf16<<<dim3(NTOK * D_MODEL / (256 * 8)), 256, 0, stream>>>(x, xbf);
    transpose_w<<<dim3(32, 40), 256, 0, stream>>>(Wq, WT, D_MODEL, 2048);
    transpose_w<<<dim3(16, 40), 256, 0, stream>>>(Wk, WT + (size_t)2048 * D_MODEL, D_MODEL, 1024);
    transpose_w<<<dim3(16, 40), 256, 0, stream>>>(Wv, WT + (size_t)3072 * D_MODEL, D_MODEL, 1024);
    gemm_fast<0><<<dim3(32, 32), 256, 0, stream>>>(xbf, D_MODEL, WT, D_MODEL, qkv, NQKV, D_MODEL);
    rmsnorm_qk<<<dim3(12288), 256, 0, stream>>>(qkv, q_scale, k_scale);
    v_transpose<<<dim3(4, 32, 8), 256, 0, stream>>>(qkv, xbf);   // Vt in xbf slot
    attn_fused<<<dim3(T_SEQ / 64, 8, 2), 256, 0, stream>>>(qkv, xbf);
    transpose_w<<<dim3(40, 32), 256, 0, stream>>>(Wo, WT, 2048, D_MODEL);
    gemm_fast<1><<<dim3(20, 32), 256, 0, stream>>>(qkv, NQKV, WT, 2048, d_out, D_MODEL, 2048);
  } else {
    // ---- fallback (44 MB, round-5 structure + upgraded out-proj) ----
    u16* WT = qkv + (size_t)NTOK * NQKV;                   // 10.5 MB scratch
    transpose_w<<<dim3(32, 40), 256, 0, stream>>>(Wq, WT, D_MODEL, 2048);
    gemm_f32a<<<dim3(16, 32), 256, 0, stream>>>(x, D_MODEL, WT, D_MODEL, qkv, NQKV, D_MODEL);
    transpose_w<<<dim3(16, 40), 256, 0, stream>>>(Wk, WT, D_MODEL, 1024);
    gemm_f32a<<<dim3(8, 32), 256, 0, stream>>>(x, D_MODEL, WT, D_MODEL, qkv + 2048, NQKV, D_MODEL);
    transpose_w<<<dim3(16, 40), 256, 0, stream>>>(Wv, WT, D_MODEL, 1024);
    gemm_f32a<<<dim3(8, 32), 256, 0, stream>>>(x, D_MODEL, WT, D_MODEL, qkv + 3072, NQKV, D_MODEL);
    rmsnorm_qk<<<dim3(12288), 256, 0, stream>>>(qkv, q_scale, k_scale);
    v_transpose<<<dim3(4, 32, 8), 256, 0, stream>>>(qkv, WT);
    attn_fused<<<dim3(T_SEQ / 64, 8, 2), 256, 0, stream>>>(qkv, WT);
    transpose_w<<<dim3(40, 32), 256, 0, stream>>>(Wo, WT, 2048, D_MODEL);
    gemm_fast<1><<<dim3(20, 32), 256, 0, stream>>>(qkv, NQKV, WT, 2048, d_out, D_MODEL, 2048);
  }
}